// Round 1
// baseline (159.168 us; speedup 1.0000x reference)
//
#include <hip/hip_runtime.h>

#define BK 32
#define GEMM_THREADS 512
#define NBLK 256

typedef float f32x4 __attribute__((ext_vector_type(4)));
typedef short s16x8 __attribute__((ext_vector_type(8)));

__device__ __forceinline__ unsigned short f2bf(float f) {
  union { float f; unsigned u; } v; v.f = f;
  unsigned r = v.u + 0x7FFFu + ((v.u >> 16) & 1u);  // RTNE
  return (unsigned short)(r >> 16);
}

__global__ void __launch_bounds__(256) zero_kernel(float* out, float* ws, long long nws) {
  long long idx = (long long)blockIdx.x * blockDim.x + threadIdx.x;
  if (idx == 0) out[0] = 0.f;
  for (long long k = idx; k < nws; k += (long long)gridDim.x * blockDim.x) ws[k] = 0.f;
}

// Split-K GEMM: block b computes partial C[256][256] over K-chunk [b*KC, (b+1)*KC)
// C[i][j] = sum_k V1[i][k] * V2[j][k]  (both operands loaded with the symmetric
// "row, k-group" MFMA fragment pattern — any k-permutation cancels since it is
// identical for A and B).
__global__ void __launch_bounds__(GEMM_THREADS, 2)
gemm_kernel(const float* __restrict__ V1, const float* __restrict__ V2,
            float* __restrict__ ws, int D, int KC, int P, int useAtomic) {
  // [buf][mat][row][40 ushorts]; 32 bf16 data + 8 pad -> row stride 80 B
  // (80 = 16*5: 16B-aligned, and 20r mod 32 hits 8 distinct banks per 8 rows)
  __shared__ __align__(16) unsigned short lds[2 * 2 * 256 * 40];  // 80 KiB

  const int tid  = threadIdx.x;
  const int lane = tid & 63;
  const int wid  = tid >> 6;
  const int wm   = wid >> 2;   // 0..1  (M wave)
  const int wn   = wid & 3;    // 0..3  (N wave)
  const int lr   = lane & 15;  // fragment row/col
  const int lg   = lane >> 4;  // k-group 0..3

  const int r0 = tid >> 3;     // staging base row 0..63
  const int c8 = tid & 7;      // 16B segment within row
  const int nsteps = KC / BK;

  f32x4 acc[8][4];
#pragma unroll
  for (int a = 0; a < 8; ++a)
#pragma unroll
    for (int b = 0; b < 4; ++b) acc[a][b] = f32x4{0.f, 0.f, 0.f, 0.f};

  // precompute per-thread global base pointers (4 rows each, stride 64)
  const float* pA[4];
  const float* pB[4];
  {
    const size_t kbase = (size_t)blockIdx.x * (size_t)KC + (size_t)c8 * 4;
#pragma unroll
    for (int q = 0; q < 4; ++q) {
      size_t r = (size_t)(r0 + 64 * q);
      pA[q] = V1 + r * (size_t)D + kbase;
      pB[q] = V2 + r * (size_t)D + kbase;
    }
  }

  float4 sa[4], sb[4];

  auto issue = [&](int t) {
#pragma unroll
    for (int q = 0; q < 4; ++q) {
      sa[q] = *(const float4*)(pA[q] + (size_t)t * BK);
      sb[q] = *(const float4*)(pB[q] + (size_t)t * BK);
    }
  };
  auto lwrite = [&](int buf) {
#pragma unroll
    for (int q = 0; q < 4; ++q) {
      int r  = r0 + 64 * q;
      int ua = (buf * 2 + 0) * 256 * 40 + r * 40 + c8 * 4;
      int ub = (buf * 2 + 1) * 256 * 40 + r * 40 + c8 * 4;
      ushort4 wa, wb;
      wa.x = f2bf(sa[q].x); wa.y = f2bf(sa[q].y); wa.z = f2bf(sa[q].z); wa.w = f2bf(sa[q].w);
      wb.x = f2bf(sb[q].x); wb.y = f2bf(sb[q].y); wb.z = f2bf(sb[q].z); wb.w = f2bf(sb[q].w);
      *(ushort4*)&lds[ua] = wa;
      *(ushort4*)&lds[ub] = wb;
    }
  };

  issue(0);
  lwrite(0);
  if (nsteps > 1) issue(1);
  __syncthreads();

  for (int t = 0; t < nsteps; ++t) {
    const int buf = t & 1;

    s16x8 af[8], bfr[4];
#pragma unroll
    for (int mf = 0; mf < 8; ++mf) {
      int r = wm * 128 + mf * 16 + lr;
      af[mf] = *(const s16x8*)&lds[(buf * 2 + 0) * 256 * 40 + r * 40 + lg * 8];
    }
#pragma unroll
    for (int nf = 0; nf < 4; ++nf) {
      int r = wn * 64 + nf * 16 + lr;
      bfr[nf] = *(const s16x8*)&lds[(buf * 2 + 1) * 256 * 40 + r * 40 + lg * 8];
    }
#pragma unroll
    for (int mf = 0; mf < 8; ++mf)
#pragma unroll
      for (int nf = 0; nf < 4; ++nf)
        acc[mf][nf] = __builtin_amdgcn_mfma_f32_16x16x32_bf16(af[mf], bfr[nf], acc[mf][nf], 0, 0, 0);

    if (t + 1 < nsteps) {
      lwrite(buf ^ 1);              // waits vmcnt for loads(t+1), writes other buffer
      if (t + 2 < nsteps) issue(t + 2);  // stays in flight across the barrier
    }
    __syncthreads();
  }

  // C/D layout (m89-verified): col = lane&15, row = (lane>>4)*4 + reg
  float* Cp = ws + (size_t)(blockIdx.x % (unsigned)P) * (256 * 256);
#pragma unroll
  for (int mf = 0; mf < 8; ++mf) {
    int i0 = wm * 128 + mf * 16 + lg * 4;
#pragma unroll
    for (int nf = 0; nf < 4; ++nf) {
      int j = wn * 64 + nf * 16 + lr;
#pragma unroll
      for (int v = 0; v < 4; ++v) {
        int off = (i0 + v) * 256 + j;
        if (useAtomic) atomicAdd(&Cp[off], acc[mf][nf][v]);
        else           Cp[off] = acc[mf][nf][v];
      }
    }
  }
}

// Sum P partials, z = dot/D, BCE vs identity labels:
//   diag: -log(sigmoid(z))  = softplus(z) - z
//   off :  -log(1-sigmoid(z)) = softplus(z)
__global__ void __launch_bounds__(256)
loss_kernel(const float* __restrict__ ws, float* __restrict__ out, int P, float invD) {
  const int i = blockIdx.x, j = threadIdx.x;
  const float* base = ws + i * 256 + j;
  float s = 0.f;
#pragma unroll 8
  for (int p = 0; p < P; ++p) s += base[(size_t)p * 65536];
  float z = s * invD;
  float term = log1pf(expf(z)) - (i == j ? z : 0.f);

  __shared__ float red[256];
  red[j] = term;
  __syncthreads();
  for (int st = 128; st > 0; st >>= 1) {
    if (j < st) red[j] += red[j + st];
    __syncthreads();
  }
  if (j == 0) atomicAdd(out, red[0] * (1.f / 65536.f));
}

extern "C" void kernel_launch(void* const* d_in, const int* in_sizes, int n_in,
                              void* d_out, int out_size, void* d_ws, size_t ws_size,
                              hipStream_t stream) {
  const float* V1 = (const float*)d_in[0];
  const float* V2 = (const float*)d_in[1];
  float* out = (float*)d_out;
  float* ws  = (float*)d_ws;

  const int N = 256;
  const int D = in_sizes[0] / N;     // 262144
  const int KC = D / NBLK;           // 1024

  long long cap = (long long)(ws_size / (sizeof(float) * 65536));
  int P = (int)(cap >= NBLK ? NBLK : (cap < 1 ? 1 : cap));
  int useAtomic = (P < NBLK) ? 1 : 0;
  long long nws = useAtomic ? (long long)P * 65536 : 0;

  zero_kernel<<<64, 256, 0, stream>>>(out, ws, nws);
  gemm_kernel<<<NBLK, GEMM_THREADS, 0, stream>>>(V1, V2, ws, D, KC, P, useAtomic);
  loss_kernel<<<N, 256, 0, stream>>>(ws, out, P, 1.0f / (float)D);
}